// Round 17
// baseline (170.489 us; speedup 1.0000x reference)
//
#include <hip/hip_runtime.h>

#define EPSV 1e-5f

constexpr int kB = 16, kC = 3, kT = 256, kV = 25;
constexpr int kMID = 48, kNB = 4, kOUT = 192, kN = 48;
constexpr int kS  = kB * kT * kV;   // 102400 sites
constexpr int kTV = kT * kV;        // 6400

typedef __attribute__((ext_vector_type(8))) short bf16x8;
typedef __attribute__((ext_vector_type(4))) float f32x4;

__device__ __forceinline__ short f2bf(float f) {
  unsigned u = __float_as_uint(f);
  u += 0x7fffu + ((u >> 16) & 1u);          // RNE
  return (short)(u >> 16);
}
__device__ __forceinline__ float bf2f(short s) {
  return __uint_as_float(((unsigned)(unsigned short)s) << 16);
}
__device__ __forceinline__ float wred(float v) {
  #pragma unroll
  for (int d = 32; d > 0; d >>= 1) v += __shfl_xor(v, d);
  return v;
}

// ws layout (floats): XMOM 0(9) | H0MOM 16(65) | ST2 96(20) | ST3 128(2)
// | XG 608(3072) | XGT 3680(3072) | ACC bf16 @8192 (512000f) |
// Y3 bf16 @520192 (51200f) | WBBF @571392 (249600f) | XSG @820992 (253440f)

// ---- K0: zero stats region (replaces hipMemsetAsync -- R15 profile showed the
// runtime's 2.4KB fillBufferAligned costing ~41us/replay, same as a 262MB fill).
// Zeroing 608..767 touches XG's head, which head2 fully overwrites before reads.
__global__ __launch_bounds__(256) void zero_stats(float* __restrict__ ws)
{
  ws[blockIdx.x * 256 + threadIdx.x] = 0.f;   // grid 3*256 = 768
}

__device__ __forceinline__ void st0_from_xmom(int o, const float* fw0, const float* fb0,
                                              const float* fg0, const float* fbe0,
                                              const float* xmom, float* sc0, float* sh0)
{
  float w0 = fw0[o * 3], w1 = fw0[o * 3 + 1], w2 = fw0[o * 3 + 2], b = fb0[o];
  float Sw = w0 * xmom[0] + w1 * xmom[1] + w2 * xmom[2];
  float Q  = w0*w0*xmom[3] + w1*w1*xmom[6] + w2*w2*xmom[8]
           + 2.f*(w0*w1*xmom[4] + w0*w2*xmom[5] + w1*w2*xmom[7]);
  float mean = (Sw + (float)kS * b) * (1.f / kS);
  float e2   = (Q + 2.f * b * Sw) * (1.f / kS) + b * b;
  float var  = e2 - mean * mean;
  float sc   = fg0[o] * rsqrtf(var + EPSV);
  sc0[o] = sc; sh0[o] = fbe0[o] - mean * sc;
}

__device__ __forceinline__ void st1_analytic(int o, const float* w1p, const float* fg1,
                                             const float* fbe1, const float* H0MOM,
                                             float* sc1, float* sh1)
{
  float wr[10]; float S = 0.f, Q = 0.f;
  #pragma unroll
  for (int c = 0; c < 10; c++) { wr[c] = w1p[o*12+c]; S = fmaf(wr[c], H0MOM[c], S); }
  int idx = 10;
  #pragma unroll
  for (int c = 0; c < 10; c++) {
    Q = fmaf(wr[c]*wr[c], H0MOM[idx], Q); idx++;
    #pragma unroll
    for (int cp = c + 1; cp < 10; cp++) { Q = fmaf(2.f*wr[c]*wr[cp], H0MOM[idx], Q); idx++; }
  }
  float b = w1p[o*12+10];
  float mean = (S + (float)kS * b) * (1.f / kS);
  float e2   = (Q + 2.f * b * S) * (1.f / kS) + b * b;
  float var  = e2 - mean * mean;
  float sc   = fg1[o] * rsqrtf(var + EPSV);
  sc1[o] = sc; sh1[o] = fbe1[o] - mean * sc;
}

// ---- K1: prep bf16 conv operands + x moments ----
__global__ __launch_bounds__(128) void prep_xmom(
    const float* __restrict__ x, const float* __restrict__ Wb,
    short* __restrict__ XSG, short* __restrict__ WBBF, float* __restrict__ xmom)
{
  __shared__ float red[9];
  const int tid = threadIdx.x;
  const int gtid = blockIdx.x * 128 + tid;      // 102400 threads

  for (int j = gtid; j < 48 * 10560; j += 102400) {     // XSG[n][row 264][ci 40]
    int n = j / 10560, rem = j - n * 10560;
    int row = rem / 40, ci = rem - row * 40;
    short val = 0;
    if (row >= 8 && ci < 25) val = f2bf(x[n * 6400 + (row - 8) * 25 + ci]);
    XSG[j] = val;
  }
  for (int j = gtid; j < 499200; j += 102400) {         // WBBF[(i*25+v)][m][kk 104]
    int g = j / 4992, rem = j - g * 4992;
    int m = rem / 104, kk = rem - m * 104;
    int k = kk >> 5, ci = kk & 31;
    short val = 0;
    if (ci < 25 && kk < 96) val = f2bf(Wb[g * 3600 + m * 75 + ci * 3 + k]);
    WBBF[j] = val;
  }

  if (tid < 9) red[tid] = 0.f;
  __syncthreads();
  const int s = gtid;
  const int b = s / kTV, r = s - b * kTV;
  const float x0 = x[(b * 3 + 0) * kTV + r];
  const float x1 = x[(b * 3 + 1) * kTV + r];
  const float x2 = x[(b * 3 + 2) * kTV + r];
  const float pm[9] = {x0, x1, x2, x0*x0, x0*x1, x0*x2, x1*x1, x1*x2, x2*x2};
  #pragma unroll
  for (int k = 0; k < 9; k++) {
    float t = wred(pm[k]);
    if ((tid & 63) == 0) atomicAdd(&red[k], t);
  }
  __syncthreads();
  if (tid < 9) atomicAdd(&xmom[tid], red[tid]);
}

// ---- K2: h0 moments ----
__global__ __launch_bounds__(128) void h0mom_kernel(
    const float* __restrict__ x,
    const float* __restrict__ fw0, const float* __restrict__ fb0,
    const float* __restrict__ fg0, const float* __restrict__ fbe0,
    const float* __restrict__ xmom, float* __restrict__ h0mom)
{
  __shared__ __align__(16) float w0p[40];
  __shared__ float sc0[10], sh0[10];
  __shared__ float red[65];
  const int tid = threadIdx.x;
  for (int j = tid; j < 40; j += 128) {
    int o = j >> 2, c = j & 3;
    w0p[j] = (c < 3) ? fw0[o * 3 + c] : fb0[o];
  }
  if (tid < 10) st0_from_xmom(tid, fw0, fb0, fg0, fbe0, xmom, sc0, sh0);
  if (tid < 65) red[tid] = 0.f;
  __syncthreads();
  const int s = blockIdx.x * 128 + tid;
  const int b = s / kTV, r = s - b * kTV;
  const float x0 = x[(b * 3 + 0) * kTV + r];
  const float x1 = x[(b * 3 + 1) * kTV + r];
  const float x2 = x[(b * 3 + 2) * kTV + r];
  float h0[10];
  #pragma unroll
  for (int o = 0; o < 10; o++) {
    const float4 w = *(const float4*)&w0p[o * 4];
    float y = fmaf(x0, w.x, fmaf(x1, w.y, fmaf(x2, w.z, w.w)));
    h0[o] = fmaxf(fmaf(y, sc0[o], sh0[o]), 0.f);
  }
  int idx = 0;
  #pragma unroll
  for (int c = 0; c < 10; c++) {
    float t = wred(h0[c]);
    if ((tid & 63) == 0) atomicAdd(&red[idx], t);
    idx++;
  }
  #pragma unroll
  for (int c = 0; c < 10; c++)
    #pragma unroll
    for (int cp = c; cp < 10; cp++) {
      float t = wred(h0[c] * h0[cp]);
      if ((tid & 63) == 0) atomicAdd(&red[idx], t);
      idx++;
    }
  __syncthreads();
  if (tid < 65) atomicAdd(&h0mom[tid], red[tid]);
}

// ---- K3: single 100-ch stream; write raw layer2 ACC (bf16) + ST2 stats ----
__global__ __launch_bounds__(128) void st2acc(
    const float* __restrict__ x,
    const float* __restrict__ fw0, const float* __restrict__ fb0,
    const float* __restrict__ fg0, const float* __restrict__ fbe0,
    const float* __restrict__ fw1, const float* __restrict__ fb1,
    const float* __restrict__ fg1, const float* __restrict__ fbe1,
    const float* __restrict__ fw2, const float* __restrict__ fb2,
    const float* __restrict__ xmom, const float* __restrict__ h0mom,
    short* __restrict__ accout, float* __restrict__ st2out)
{
  __shared__ __align__(16) float w0p[40];
  __shared__ __align__(16) float w1p[1200];  // [o][12]: 10w, bias, pad
  __shared__ __align__(16) float w2t[1200];  // [c][12]
  __shared__ float b2s[10];
  __shared__ float sc0[10], sh0[10], sc1[100], sh1[100];
  __shared__ float red[20];
  const int tid = threadIdx.x;

  for (int j = tid; j < 40; j += 128) {
    int o = j >> 2, c = j & 3;
    w0p[j] = (c < 3) ? fw0[o * 3 + c] : fb0[o];
  }
  for (int j = tid; j < 1200; j += 128) {
    int o = j / 12, c = j - o * 12;
    w1p[j] = (c < 10) ? fw1[o * 10 + c] : (c == 10 ? fb1[o] : 0.f);
  }
  for (int j = tid; j < 1000; j += 128) {
    int jj = j / 100, c = j - jj * 100;
    w2t[c * 12 + jj] = fw2[j];
  }
  for (int c = tid; c < 100; c += 128) { w2t[c * 12 + 10] = 0.f; w2t[c * 12 + 11] = 0.f; }
  if (tid < 10) {
    b2s[tid] = fb2[tid];
    st0_from_xmom(tid, fw0, fb0, fg0, fbe0, xmom, sc0, sh0);
  }
  if (tid < 20) red[tid] = 0.f;
  __syncthreads();
  if (tid < 100) st1_analytic(tid, w1p, fg1, fbe1, h0mom, sc1, sh1);
  __syncthreads();

  const int s = blockIdx.x * 128 + tid;    // 800 blocks cover kS
  const int b = s / kTV, r = s - b * kTV;
  const float x0 = x[(b * 3 + 0) * kTV + r];
  const float x1 = x[(b * 3 + 1) * kTV + r];
  const float x2 = x[(b * 3 + 2) * kTV + r];
  float h0[10];
  #pragma unroll
  for (int o = 0; o < 10; o++) {
    const float4 w = *(const float4*)&w0p[o * 4];
    float y = fmaf(x0, w.x, fmaf(x1, w.y, fmaf(x2, w.z, w.w)));
    h0[o] = fmaxf(fmaf(y, sc0[o], sh0[o]), 0.f);
  }
  float acc[10];
  #pragma unroll
  for (int o = 0; o < 10; o++) acc[o] = b2s[o];
  #pragma unroll 4
  for (int o = 0; o < 100; o++) {
    const float4 wa = *(const float4*)&w1p[o * 12];
    const float4 wb = *(const float4*)&w1p[o * 12 + 4];
    const float4 wc = *(const float4*)&w1p[o * 12 + 8];
    float a = wc.z;
    a = fmaf(h0[0], wa.x, a); a = fmaf(h0[1], wa.y, a);
    a = fmaf(h0[2], wa.z, a); a = fmaf(h0[3], wa.w, a);
    a = fmaf(h0[4], wb.x, a); a = fmaf(h0[5], wb.y, a);
    a = fmaf(h0[6], wb.z, a); a = fmaf(h0[7], wb.w, a);
    a = fmaf(h0[8], wc.x, a); a = fmaf(h0[9], wc.y, a);
    const float h1 = fmaxf(fmaf(a, sc1[o], sh1[o]), 0.f);
    const float4 va = *(const float4*)&w2t[o * 12];
    const float4 vb = *(const float4*)&w2t[o * 12 + 4];
    const float4 vc = *(const float4*)&w2t[o * 12 + 8];
    acc[0] = fmaf(h1, va.x, acc[0]); acc[1] = fmaf(h1, va.y, acc[1]);
    acc[2] = fmaf(h1, va.z, acc[2]); acc[3] = fmaf(h1, va.w, acc[3]);
    acc[4] = fmaf(h1, vb.x, acc[4]); acc[5] = fmaf(h1, vb.y, acc[5]);
    acc[6] = fmaf(h1, vb.z, acc[6]); acc[7] = fmaf(h1, vb.w, acc[7]);
    acc[8] = fmaf(h1, vc.x, acc[8]); acc[9] = fmaf(h1, vc.y, acc[9]);
  }
  #pragma unroll
  for (int o = 0; o < 10; o++) accout[o * kS + s] = f2bf(acc[o]);
  #pragma unroll
  for (int o = 0; o < 10; o++) {
    float s1 = wred(acc[o]), s2 = wred(acc[o] * acc[o]);
    if ((tid & 63) == 0) { atomicAdd(&red[2 * o], s1); atomicAdd(&red[2 * o + 1], s2); }
  }
  __syncthreads();
  if (tid < 20) atomicAdd(&st2out[tid], red[tid]);
}

// ---- K4: h2/y3 from ACC (memory-light); direct y3 stats ----
__global__ __launch_bounds__(128) void h2y3(
    const short* __restrict__ ACC,
    const float* __restrict__ fg2, const float* __restrict__ fbe2,
    const float* __restrict__ fw3, const float* __restrict__ fb3,
    const float* __restrict__ st2,
    short* __restrict__ y3out, float* __restrict__ st3out)
{
  __shared__ float sc2[10], sh2[10], w3s[12];
  __shared__ float red[2];
  const int tid = threadIdx.x;
  if (tid < 10) {
    float m  = st2[2 * tid] * (1.f / kS);
    float vr = st2[2 * tid + 1] * (1.f / kS) - m * m;
    float sc = fg2[tid] * rsqrtf(vr + EPSV);
    sc2[tid] = sc; sh2[tid] = fbe2[tid] - m * sc;
  }
  if (tid < 12) w3s[tid] = (tid < 10) ? fw3[tid] : (tid == 10 ? fb3[0] : 0.f);
  if (tid < 2) red[tid] = 0.f;
  __syncthreads();
  const int s = blockIdx.x * 128 + tid;
  float y3 = w3s[10];
  #pragma unroll
  for (int o = 0; o < 10; o++) {
    float h2 = fmaxf(fmaf(bf2f(ACC[o * kS + s]), sc2[o], sh2[o]), 0.f);
    y3 = fmaf(h2, w3s[o], y3);
  }
  y3out[s] = f2bf(y3);
  float s1 = wred(y3), s2 = wred(y3 * y3);
  if ((tid & 63) == 0) { atomicAdd(&red[0], s1); atomicAdd(&red[1], s2); }
  __syncthreads();
  if (tid < 2) atomicAdd(&st3out[tid], red[tid]);
}

// ---- K5: head2 = bn3+relu+T-pool (from Y3) + FC head (1 block) ----
// Pool phase: register accumulation + 16-lane butterfly (R14 lesson: 1-block
// LDS-atomic pool was a 200us serialized chain).
__global__ __launch_bounds__(256) void head2_kernel(
    const short* __restrict__ y3, const float* __restrict__ st3,
    const float* __restrict__ fg3, const float* __restrict__ fbe3,
    const float* __restrict__ cw0, const float* __restrict__ cb0,
    const float* __restrict__ cg0, const float* __restrict__ cbe0,
    const float* __restrict__ cw1, const float* __restrict__ cb1,
    const float* __restrict__ cg1, const float* __restrict__ cbe1,
    float* __restrict__ xg, float* __restrict__ xgT, float* __restrict__ reg_out)
{
  __shared__ float scsh[2];
  __shared__ float hpl[400];
  __shared__ float y1[100 * 16];
  __shared__ float y2l[192 * 16];
  const int tid = threadIdx.x;
  if (tid == 0) {
    reg_out[0] = 0.f;                      // zero reg scalar (gcreg runs after)
    float m  = st3[0] * (1.f / kS);
    float vr = st3[1] * (1.f / kS) - m * m;
    float sc = fg3[0] * rsqrtf(vr + EPSV);
    scsh[0] = sc; scsh[1] = fbe3[0] - m * sc;
  }
  __syncthreads();
  {
    const float sc = scsh[0], sh = scsh[1];
    float ps[25];
    #pragma unroll
    for (int vv = 0; vv < 25; vv++) ps[vv] = 0.f;
    #pragma unroll
    for (int it = 0; it < 50; it++) {
      const int base = tid * 400 + it * 8;
      const bf16x8 v8 = *(const bf16x8*)&y3[base];
      #pragma unroll
      for (int e = 0; e < 8; e++) {
        const int vv = (it * 8 + e) % 25;          // compile-time per (it,e)
        ps[vv] += fmaxf(fmaf(bf2f(v8[e]), sc, sh), 0.f);
      }
    }
    #pragma unroll
    for (int vv = 0; vv < 25; vv++) {
      float v = ps[vv];
      v += __shfl_xor(v, 1); v += __shfl_xor(v, 2);
      v += __shfl_xor(v, 4); v += __shfl_xor(v, 8);
      if ((tid & 15) == 0) hpl[(tid >> 4) * 25 + vv] = v * (1.f / kT);  // b = tid/16
    }
  }
  __syncthreads();
  for (int j = tid; j < 1600; j += 256) {
    int o = j >> 4, b = j & 15;
    float acc = cb0[o];
    for (int v = 0; v < 25; v++) acc = fmaf(hpl[b * 25 + v], cw0[o * 25 + v], acc);
    y1[o * 16 + b] = acc;
  }
  __syncthreads();
  if (tid < 100) {
    float s1 = 0.f, s2 = 0.f;
    for (int b = 0; b < 16; b++) { float val = y1[tid * 16 + b]; s1 += val; s2 += val * val; }
    float m = s1 * (1.f / 16), vr = s2 * (1.f / 16) - m * m;
    float scale = cg0[tid] * rsqrtf(vr + EPSV);
    float shift = cbe0[tid] - m * scale;
    for (int b = 0; b < 16; b++)
      y1[tid * 16 + b] = fmaxf(fmaf(y1[tid * 16 + b], scale, shift), 0.f);
  }
  __syncthreads();
  for (int j = tid; j < 3072; j += 256) {
    int o = j >> 4, b = j & 15;
    float acc = cb1[o];
    for (int c = 0; c < 100; c++) acc = fmaf(y1[c * 16 + b], cw1[o * 100 + c], acc);
    y2l[o * 16 + b] = acc;
  }
  __syncthreads();
  if (tid < 192) {
    float s1 = 0.f, s2 = 0.f;
    for (int b = 0; b < 16; b++) { float val = y2l[tid * 16 + b]; s1 += val; s2 += val * val; }
    float m = s1 * (1.f / 16), vr = s2 * (1.f / 16) - m * m;
    float scale = cg1[tid] * rsqrtf(vr + EPSV);
    float shift = cbe1[tid] - m * scale;
    for (int b = 0; b < 16; b++) {
      float r = fmaxf(fmaf(y2l[tid * 16 + b], scale, shift), 0.f);
      xg[b * 192 + tid]  = r;
      xgT[tid * 16 + b]  = r;
    }
  }
}

// ---- K6: gc/reg (625 blocks) ----
__global__ __launch_bounds__(64) void gcreg_kernel(
    const float* __restrict__ Wb, const float* __restrict__ XGT,
    float* __restrict__ gc_out, float* __restrict__ reg_out)
{
  __shared__ float sW[576];
  __shared__ float sG[192 * 17];
  const int tid = threadIdx.x;
  const int v1 = blockIdx.x / 25, v2 = blockIdx.x % 25;
  for (int j = tid; j < 3072; j += 64) {
    int o = j >> 4, bq = j & 15;
    sG[o * 17 + bq] = XGT[j];
  }
  for (int p = tid; p < 192; p += 64) {
    int i = p / 48, m = p - i * 48;
    const float* src = Wb + ((i * 25 + v1) * 48 + m) * 75 + v2 * 3;
    sW[p * 3 + 0] = src[0]; sW[p * 3 + 1] = src[1]; sW[p * 3 + 2] = src[2];
  }
  __syncthreads();
  const int b = tid & 15, c = tid >> 4;
  float s0 = 0.f, s1 = 0.f, s2 = 0.f, mx = -3.0e38f;
  #pragma unroll 4
  for (int o = c * 48; o < c * 48 + 48; o++) {
    float g = sG[o * 17 + b];
    float a0 = sW[o * 3] * g, a1 = sW[o * 3 + 1] * g, a2 = sW[o * 3 + 2] * g;
    s0 = fmaf(a0, a0, s0);
    s1 = fmaf(a1, a1, s1);
    s2 = fmaf(a2, a2, s2);
    mx = fmaxf(mx, fmaxf(fmaxf(a0, a1), a2));
  }
  s0 += __shfl_xor(s0, 16); s0 += __shfl_xor(s0, 32);
  s1 += __shfl_xor(s1, 16); s1 += __shfl_xor(s1, 32);
  s2 += __shfl_xor(s2, 16); s2 += __shfl_xor(s2, 32);
  mx = fmaxf(mx, __shfl_xor(mx, 16)); mx = fmaxf(mx, __shfl_xor(mx, 32));
  float contrib = 0.f;
  if (c == 0) {
    gc_out[(b * 25 + v1) * 25 + v2] = mx;
    contrib = sqrtf(s0 + s1 + s2) + sqrtf(s0) + sqrtf(s1) + sqrtf(s2);
  }
  #pragma unroll
  for (int d = 1; d < 16; d <<= 1) contrib += __shfl_xor(contrib, d);
  if (tid == 0) atomicAdd(reg_out, 0.01f * contrib);
}

// ---- K7: MFMA fused dilated conv + gate + relu + Ww-dot + loss ----
// gw built in-block from XG x Ww (GW tensor eliminated).
__global__ __launch_bounds__(256) void conv_fuse_mfma(
    const short* __restrict__ XSG, const short* __restrict__ WBBF,
    const float* __restrict__ XG, const float* __restrict__ Ww,
    const float* __restrict__ x, const float* __restrict__ bb,
    const float* __restrict__ bw, float* __restrict__ out_loss)
{
  __shared__ __align__(16) short xs[264 * 40];    // 21120 B
  __shared__ __align__(16) short As[48 * 104];    // 9984 B
  __shared__ __align__(16) float gw[25 * 204];    // 20400 B, stride 204
  __shared__ float bbl[192], bwl[32];

  const int tid = threadIdx.x;
  const int v = blockIdx.x % 25, n = blockIdx.x / 25;
  const int bidx = n / 3;

  {
    const uint4* src = (const uint4*)(XSG + n * 10560);
    uint4* dst = (uint4*)xs;
    for (int j = tid; j < 1320; j += 256) dst[j] = src[j];
  }
  for (int j = tid; j < 4800; j += 256) {          // gw = XG[bidx] * Ww
    int vv = j / 192, o = j - vv * 192;
    gw[vv * 204 + o] = XG[bidx * 192 + o] * Ww[j];
  }
  for (int j = tid; j < 192; j += 256) {
    int i = j / 48, m = j - i * 48;
    bbl[j] = bb[(i * 25 + v) * 48 + m];
  }
  if (tid < 25) bwl[tid] = bw[tid];

  const int lane = tid & 63, w = tid >> 6;
  const int c = lane & 15, q = lane >> 4;

  float accout[4] = {0.f, 0.f, 0.f, 0.f};
  int tarr[4], vparr[4];
  #pragma unroll
  for (int z = 0; z < 4; z++) {
    int t = (w * 4 + z) * 16 + c;
    tarr[z] = t;
    vparr[z] = (v * 256 + t) % 25;
  }

  for (int i = 0; i < 4; i++) {
    __syncthreads();                               // covers initial staging too
    {
      const uint4* src = (const uint4*)(WBBF + (i * 25 + v) * 4992);
      uint4* dst = (uint4*)As;
      for (int j = tid; j < 624; j += 256) dst[j] = src[j];
    }
    __syncthreads();

    const int d = i + 1;
    bf16x8 af[3][3];
    #pragma unroll
    for (int mt = 0; mt < 3; mt++)
      #pragma unroll
      for (int s = 0; s < 3; s++)
        af[mt][s] = *(const bf16x8*)&As[(mt * 16 + c) * 104 + s * 32 + q * 8];

    #pragma unroll
    for (int z = 0; z < 4; z++) {
      const int t = tarr[z];
      bf16x8 bfv[3];
      #pragma unroll
      for (int s = 0; s < 3; s++) {
        int row = 8 + t + (s - 2) * d;             // taps at t-2d, t-d, t
        bfv[s] = *(const bf16x8*)&xs[row * 40 + q * 8];
      }
      f32x4 acc[3] = {{0.f,0.f,0.f,0.f},{0.f,0.f,0.f,0.f},{0.f,0.f,0.f,0.f}};
      #pragma unroll
      for (int s = 0; s < 3; s++)
        #pragma unroll
        for (int mt = 0; mt < 3; mt++)
          acc[mt] = __builtin_amdgcn_mfma_f32_16x16x32_bf16(af[mt][s], bfv[s], acc[mt], 0, 0, 0);
      const int vp = vparr[z];
      float aout = 0.f;
      #pragma unroll
      for (int mt = 0; mt < 3; mt++) {
        const int ob = i * 48 + mt * 16 + q * 4;
        const float4 g4 = *(const float4*)&gw[vp * 204 + ob];
        float v0 = fmaxf(acc[mt][0] + bbl[ob + 0], 0.f);
        float v1 = fmaxf(acc[mt][1] + bbl[ob + 1], 0.f);
        float v2 = fmaxf(acc[mt][2] + bbl[ob + 2], 0.f);
        float v3 = fmaxf(acc[mt][3] + bbl[ob + 3], 0.f);
        aout = fmaf(v0, g4.x, aout);
        aout = fmaf(v1, g4.y, aout);
        aout = fmaf(v2, g4.z, aout);
        aout = fmaf(v3, g4.w, aout);
      }
      accout[z] += aout;
    }
  }

  #pragma unroll
  for (int z = 0; z < 4; z++) {
    float a = accout[z];
    a += __shfl_xor(a, 16);
    a += __shfl_xor(a, 32);
    if (q == 0) {
      int flat = v * 256 + tarr[z];
      int tp = flat / 25, vp = flat - tp * 25;
      if (tp < 255) {
        float pf = a + bwl[vp];
        float xn = x[n * 6400 + (tp + 1) * 25 + vp];
        float dd = pf - xn;
        out_loss[(n * 25 + vp) * 255 + tp] = dd * dd;
      }
    }
  }
}

extern "C" void kernel_launch(void* const* d_in, const int* in_sizes, int n_in,
                              void* d_out, int out_size, void* d_ws, size_t ws_size,
                              hipStream_t stream)
{
  const float* x    = (const float*)d_in[0];
  const float* Wb   = (const float*)d_in[1];
  const float* bb   = (const float*)d_in[2];
  const float* fw0  = (const float*)d_in[3];
  const float* fb0  = (const float*)d_in[4];
  const float* fg0  = (const float*)d_in[5];
  const float* fbe0 = (const float*)d_in[6];
  const float* fw1  = (const float*)d_in[7];
  const float* fb1  = (const float*)d_in[8];
  const float* fg1  = (const float*)d_in[9];
  const float* fbe1 = (const float*)d_in[10];
  const float* fw2  = (const float*)d_in[11];
  const float* fb2  = (const float*)d_in[12];
  const float* fg2  = (const float*)d_in[13];
  const float* fbe2 = (const float*)d_in[14];
  const float* fw3  = (const float*)d_in[15];
  const float* fb3  = (const float*)d_in[16];
  const float* fg3  = (const float*)d_in[17];
  const float* fbe3 = (const float*)d_in[18];
  const float* cw0  = (const float*)d_in[19];
  const float* cb0  = (const float*)d_in[20];
  const float* cg0  = (const float*)d_in[21];
  const float* cbe0 = (const float*)d_in[22];
  const float* cw1  = (const float*)d_in[23];
  const float* cb1  = (const float*)d_in[24];
  const float* cg1  = (const float*)d_in[25];
  const float* cbe1 = (const float*)d_in[26];
  const float* Ww   = (const float*)d_in[27];
  const float* bw   = (const float*)d_in[28];

  float* ws  = (float*)d_ws;
  float* out = (float*)d_out;

  float* XMOM  = ws;                      // 9
  float* H0MOM = ws + 16;                 // 65
  float* ST2   = ws + 96;                 // 20
  float* ST3   = ws + 128;                // 2 (sum, sumsq)
  float* XG    = ws + 608;                // 3072
  float* XGT   = ws + 3680;               // 3072
  short* ACC   = (short*)(ws + 8192);     // 10*kS shorts
  short* Y3    = (short*)(ws + 520192);   // 102400 shorts
  short* WBBF  = (short*)(ws + 571392);   // 499200 shorts
  short* XSG   = (short*)(ws + 820992);   // 506880 shorts

  zero_stats<<<3, 256, 0, stream>>>(ws);   // replaces hipMemsetAsync (R15: 41us fill)

  prep_xmom<<<800, 128, 0, stream>>>(x, Wb, XSG, WBBF, XMOM);
  h0mom_kernel<<<800, 128, 0, stream>>>(x, fw0, fb0, fg0, fbe0, XMOM, H0MOM);
  st2acc<<<800, 128, 0, stream>>>(x, fw0, fb0, fg0, fbe0, fw1, fb1, fg1, fbe1,
      fw2, fb2, XMOM, H0MOM, ACC, ST2);
  h2y3<<<800, 128, 0, stream>>>(ACC, fg2, fbe2, fw3, fb3, ST2, Y3, ST3);
  head2_kernel<<<1, 256, 0, stream>>>(Y3, ST3, fg3, fbe3,
      cw0, cb0, cg0, cbe0, cw1, cb1, cg1, cbe1, XG, XGT, out + 316000);
  gcreg_kernel<<<625, 64, 0, stream>>>(Wb, XGT, out + 306000, out + 316000);
  conv_fuse_mfma<<<1200, 256, 0, stream>>>(XSG, WBBF, XG, Ww, x, bb, bw, out);
}

// Round 20
// 158.178 us; speedup vs baseline: 1.0778x; 1.0778x over previous
//
#include <hip/hip_runtime.h>

#define EPSV 1e-5f

constexpr int kB = 16, kC = 3, kT = 256, kV = 25;
constexpr int kMID = 48, kNB = 4, kOUT = 192, kN = 48;
constexpr int kS  = kB * kT * kV;   // 102400 sites
constexpr int kTV = kT * kV;        // 6400

typedef __attribute__((ext_vector_type(8))) short bf16x8;
typedef __attribute__((ext_vector_type(4))) float f32x4;

__device__ __forceinline__ short f2bf(float f) {
  unsigned u = __float_as_uint(f);
  u += 0x7fffu + ((u >> 16) & 1u);          // RNE
  return (short)(u >> 16);
}
__device__ __forceinline__ float bf2f(short s) {
  return __uint_as_float(((unsigned)(unsigned short)s) << 16);
}
__device__ __forceinline__ float wred(float v) {
  #pragma unroll
  for (int d = 32; d > 0; d >>= 1) v += __shfl_xor(v, d);
  return v;
}

// ws layout (floats): XMOM 0(9) | H0MOM 16(65) | ST2 96(20) | ST3 128(2)
// | XG 608(3072) | XGT 3680(3072) | ACC bf16 @8192 (512000f) |
// Y3 bf16 @520192 (51200f) | WBBF @571392 (249600f) | XSG @820992 (253440f)

// ---- K0: zero stats region (replaces hipMemsetAsync) ----
__global__ __launch_bounds__(256) void zero_stats(float* __restrict__ ws)
{
  ws[blockIdx.x * 256 + threadIdx.x] = 0.f;   // grid 3*256 = 768
}

__device__ __forceinline__ void st0_from_xmom(int o, const float* fw0, const float* fb0,
                                              const float* fg0, const float* fbe0,
                                              const float* xmom, float* sc0, float* sh0)
{
  float w0 = fw0[o * 3], w1 = fw0[o * 3 + 1], w2 = fw0[o * 3 + 2], b = fb0[o];
  float Sw = w0 * xmom[0] + w1 * xmom[1] + w2 * xmom[2];
  float Q  = w0*w0*xmom[3] + w1*w1*xmom[6] + w2*w2*xmom[8]
           + 2.f*(w0*w1*xmom[4] + w0*w2*xmom[5] + w1*w2*xmom[7]);
  float mean = (Sw + (float)kS * b) * (1.f / kS);
  float e2   = (Q + 2.f * b * Sw) * (1.f / kS) + b * b;
  float var  = e2 - mean * mean;
  float sc   = fg0[o] * rsqrtf(var + EPSV);
  sc0[o] = sc; sh0[o] = fbe0[o] - mean * sc;
}

__device__ __forceinline__ void st1_analytic(int o, const float* w1p, const float* fg1,
                                             const float* fbe1, const float* H0MOM,
                                             float* sc1, float* sh1)
{
  float wr[10]; float S = 0.f, Q = 0.f;
  #pragma unroll
  for (int c = 0; c < 10; c++) { wr[c] = w1p[o*12+c]; S = fmaf(wr[c], H0MOM[c], S); }
  int idx = 10;
  #pragma unroll
  for (int c = 0; c < 10; c++) {
    Q = fmaf(wr[c]*wr[c], H0MOM[idx], Q); idx++;
    #pragma unroll
    for (int cp = c + 1; cp < 10; cp++) { Q = fmaf(2.f*wr[c]*wr[cp], H0MOM[idx], Q); idx++; }
  }
  float b = w1p[o*12+10];
  float mean = (S + (float)kS * b) * (1.f / kS);
  float e2   = (Q + 2.f * b * S) * (1.f / kS) + b * b;
  float var  = e2 - mean * mean;
  float sc   = fg1[o] * rsqrtf(var + EPSV);
  sc1[o] = sc; sh1[o] = fbe1[o] - mean * sc;
}

// ---- K1: prep bf16 conv operands + x moments ----
__global__ __launch_bounds__(128) void prep_xmom(
    const float* __restrict__ x, const float* __restrict__ Wb,
    short* __restrict__ XSG, short* __restrict__ WBBF, float* __restrict__ xmom)
{
  __shared__ float red[9];
  const int tid = threadIdx.x;
  const int gtid = blockIdx.x * 128 + tid;      // 102400 threads

  for (int j = gtid; j < 48 * 10560; j += 102400) {     // XSG[n][row 264][ci 40]
    int n = j / 10560, rem = j - n * 10560;
    int row = rem / 40, ci = rem - row * 40;
    short val = 0;
    if (row >= 8 && ci < 25) val = f2bf(x[n * 6400 + (row - 8) * 25 + ci]);
    XSG[j] = val;
  }
  for (int j = gtid; j < 499200; j += 102400) {         // WBBF[(i*25+v)][m][kk 104]
    int g = j / 4992, rem = j - g * 4992;
    int m = rem / 104, kk = rem - m * 104;
    int k = kk >> 5, ci = kk & 31;
    short val = 0;
    if (ci < 25 && kk < 96) val = f2bf(Wb[g * 3600 + m * 75 + ci * 3 + k]);
    WBBF[j] = val;
  }

  if (tid < 9) red[tid] = 0.f;
  __syncthreads();
  const int s = gtid;
  const int b = s / kTV, r = s - b * kTV;
  const float x0 = x[(b * 3 + 0) * kTV + r];
  const float x1 = x[(b * 3 + 1) * kTV + r];
  const float x2 = x[(b * 3 + 2) * kTV + r];
  const float pm[9] = {x0, x1, x2, x0*x0, x0*x1, x0*x2, x1*x1, x1*x2, x2*x2};
  #pragma unroll
  for (int k = 0; k < 9; k++) {
    float t = wred(pm[k]);
    if ((tid & 63) == 0) atomicAdd(&red[k], t);
  }
  __syncthreads();
  if (tid < 9) atomicAdd(&xmom[tid], red[tid]);
}

// ---- K2: h0 moments ----
__global__ __launch_bounds__(128) void h0mom_kernel(
    const float* __restrict__ x,
    const float* __restrict__ fw0, const float* __restrict__ fb0,
    const float* __restrict__ fg0, const float* __restrict__ fbe0,
    const float* __restrict__ xmom, float* __restrict__ h0mom)
{
  __shared__ __align__(16) float w0p[40];
  __shared__ float sc0[10], sh0[10];
  __shared__ float red[65];
  const int tid = threadIdx.x;
  for (int j = tid; j < 40; j += 128) {
    int o = j >> 2, c = j & 3;
    w0p[j] = (c < 3) ? fw0[o * 3 + c] : fb0[o];
  }
  if (tid < 10) st0_from_xmom(tid, fw0, fb0, fg0, fbe0, xmom, sc0, sh0);
  if (tid < 65) red[tid] = 0.f;
  __syncthreads();
  const int s = blockIdx.x * 128 + tid;
  const int b = s / kTV, r = s - b * kTV;
  const float x0 = x[(b * 3 + 0) * kTV + r];
  const float x1 = x[(b * 3 + 1) * kTV + r];
  const float x2 = x[(b * 3 + 2) * kTV + r];
  float h0[10];
  #pragma unroll
  for (int o = 0; o < 10; o++) {
    const float4 w = *(const float4*)&w0p[o * 4];
    float y = fmaf(x0, w.x, fmaf(x1, w.y, fmaf(x2, w.z, w.w)));
    h0[o] = fmaxf(fmaf(y, sc0[o], sh0[o]), 0.f);
  }
  int idx = 0;
  #pragma unroll
  for (int c = 0; c < 10; c++) {
    float t = wred(h0[c]);
    if ((tid & 63) == 0) atomicAdd(&red[idx], t);
    idx++;
  }
  #pragma unroll
  for (int c = 0; c < 10; c++)
    #pragma unroll
    for (int cp = c; cp < 10; cp++) {
      float t = wred(h0[c] * h0[cp]);
      if ((tid & 63) == 0) atomicAdd(&red[idx], t);
      idx++;
    }
  __syncthreads();
  if (tid < 65) atomicAdd(&h0mom[tid], red[tid]);
}

// ---- K3: single 100-ch stream; write raw layer2 ACC (bf16) + ST2 stats ----
__global__ __launch_bounds__(128) void st2acc(
    const float* __restrict__ x,
    const float* __restrict__ fw0, const float* __restrict__ fb0,
    const float* __restrict__ fg0, const float* __restrict__ fbe0,
    const float* __restrict__ fw1, const float* __restrict__ fb1,
    const float* __restrict__ fg1, const float* __restrict__ fbe1,
    const float* __restrict__ fw2, const float* __restrict__ fb2,
    const float* __restrict__ xmom, const float* __restrict__ h0mom,
    short* __restrict__ accout, float* __restrict__ st2out)
{
  __shared__ __align__(16) float w0p[40];
  __shared__ __align__(16) float w1p[1200];  // [o][12]: 10w, bias, pad
  __shared__ __align__(16) float w2t[1200];  // [c][12]
  __shared__ float b2s[10];
  __shared__ float sc0[10], sh0[10], sc1[100], sh1[100];
  __shared__ float red[20];
  const int tid = threadIdx.x;

  for (int j = tid; j < 40; j += 128) {
    int o = j >> 2, c = j & 3;
    w0p[j] = (c < 3) ? fw0[o * 3 + c] : fb0[o];
  }
  for (int j = tid; j < 1200; j += 128) {
    int o = j / 12, c = j - o * 12;
    w1p[j] = (c < 10) ? fw1[o * 10 + c] : (c == 10 ? fb1[o] : 0.f);
  }
  for (int j = tid; j < 1000; j += 128) {
    int jj = j / 100, c = j - jj * 100;
    w2t[c * 12 + jj] = fw2[j];
  }
  for (int c = tid; c < 100; c += 128) { w2t[c * 12 + 10] = 0.f; w2t[c * 12 + 11] = 0.f; }
  if (tid < 10) {
    b2s[tid] = fb2[tid];
    st0_from_xmom(tid, fw0, fb0, fg0, fbe0, xmom, sc0, sh0);
  }
  if (tid < 20) red[tid] = 0.f;
  __syncthreads();
  if (tid < 100) st1_analytic(tid, w1p, fg1, fbe1, h0mom, sc1, sh1);
  __syncthreads();

  const int s = blockIdx.x * 128 + tid;    // 800 blocks cover kS
  const int b = s / kTV, r = s - b * kTV;
  const float x0 = x[(b * 3 + 0) * kTV + r];
  const float x1 = x[(b * 3 + 1) * kTV + r];
  const float x2 = x[(b * 3 + 2) * kTV + r];
  float h0[10];
  #pragma unroll
  for (int o = 0; o < 10; o++) {
    const float4 w = *(const float4*)&w0p[o * 4];
    float y = fmaf(x0, w.x, fmaf(x1, w.y, fmaf(x2, w.z, w.w)));
    h0[o] = fmaxf(fmaf(y, sc0[o], sh0[o]), 0.f);
  }
  float acc[10];
  #pragma unroll
  for (int o = 0; o < 10; o++) acc[o] = b2s[o];
  #pragma unroll 4
  for (int o = 0; o < 100; o++) {
    const float4 wa = *(const float4*)&w1p[o * 12];
    const float4 wb = *(const float4*)&w1p[o * 12 + 4];
    const float4 wc = *(const float4*)&w1p[o * 12 + 8];
    float a = wc.z;
    a = fmaf(h0[0], wa.x, a); a = fmaf(h0[1], wa.y, a);
    a = fmaf(h0[2], wa.z, a); a = fmaf(h0[3], wa.w, a);
    a = fmaf(h0[4], wb.x, a); a = fmaf(h0[5], wb.y, a);
    a = fmaf(h0[6], wb.z, a); a = fmaf(h0[7], wb.w, a);
    a = fmaf(h0[8], wc.x, a); a = fmaf(h0[9], wc.y, a);
    const float h1 = fmaxf(fmaf(a, sc1[o], sh1[o]), 0.f);
    const float4 va = *(const float4*)&w2t[o * 12];
    const float4 vb = *(const float4*)&w2t[o * 12 + 4];
    const float4 vc = *(const float4*)&w2t[o * 12 + 8];
    acc[0] = fmaf(h1, va.x, acc[0]); acc[1] = fmaf(h1, va.y, acc[1]);
    acc[2] = fmaf(h1, va.z, acc[2]); acc[3] = fmaf(h1, va.w, acc[3]);
    acc[4] = fmaf(h1, vb.x, acc[4]); acc[5] = fmaf(h1, vb.y, acc[5]);
    acc[6] = fmaf(h1, vb.z, acc[6]); acc[7] = fmaf(h1, vb.w, acc[7]);
    acc[8] = fmaf(h1, vc.x, acc[8]); acc[9] = fmaf(h1, vc.y, acc[9]);
  }
  #pragma unroll
  for (int o = 0; o < 10; o++) accout[o * kS + s] = f2bf(acc[o]);
  #pragma unroll
  for (int o = 0; o < 10; o++) {
    float s1 = wred(acc[o]), s2 = wred(acc[o] * acc[o]);
    if ((tid & 63) == 0) { atomicAdd(&red[2 * o], s1); atomicAdd(&red[2 * o + 1], s2); }
  }
  __syncthreads();
  if (tid < 20) atomicAdd(&st2out[tid], red[tid]);
}

// ---- K4: h2/y3 from ACC (memory-light); direct y3 stats ----
__global__ __launch_bounds__(128) void h2y3(
    const short* __restrict__ ACC,
    const float* __restrict__ fg2, const float* __restrict__ fbe2,
    const float* __restrict__ fw3, const float* __restrict__ fb3,
    const float* __restrict__ st2,
    short* __restrict__ y3out, float* __restrict__ st3out)
{
  __shared__ float sc2[10], sh2[10], w3s[12];
  __shared__ float red[2];
  const int tid = threadIdx.x;
  if (tid < 10) {
    float m  = st2[2 * tid] * (1.f / kS);
    float vr = st2[2 * tid + 1] * (1.f / kS) - m * m;
    float sc = fg2[tid] * rsqrtf(vr + EPSV);
    sc2[tid] = sc; sh2[tid] = fbe2[tid] - m * sc;
  }
  if (tid < 12) w3s[tid] = (tid < 10) ? fw3[tid] : (tid == 10 ? fb3[0] : 0.f);
  if (tid < 2) red[tid] = 0.f;
  __syncthreads();
  const int s = blockIdx.x * 128 + tid;
  float y3 = w3s[10];
  #pragma unroll
  for (int o = 0; o < 10; o++) {
    float h2 = fmaxf(fmaf(bf2f(ACC[o * kS + s]), sc2[o], sh2[o]), 0.f);
    y3 = fmaf(h2, w3s[o], y3);
  }
  y3out[s] = f2bf(y3);
  float s1 = wred(y3), s2 = wred(y3 * y3);
  if ((tid & 63) == 0) { atomicAdd(&red[0], s1); atomicAdd(&red[1], s2); }
  __syncthreads();
  if (tid < 2) atomicAdd(&st3out[tid], red[tid]);
}

// ---- K5: head2 = bn3+relu+T-pool (from Y3) + FC head (1 block) ----
// Pool: register accumulation + 16-lane butterfly (R14 lesson: no LDS atomics).
__global__ __launch_bounds__(256) void head2_kernel(
    const short* __restrict__ y3, const float* __restrict__ st3,
    const float* __restrict__ fg3, const float* __restrict__ fbe3,
    const float* __restrict__ cw0, const float* __restrict__ cb0,
    const float* __restrict__ cg0, const float* __restrict__ cbe0,
    const float* __restrict__ cw1, const float* __restrict__ cb1,
    const float* __restrict__ cg1, const float* __restrict__ cbe1,
    float* __restrict__ xg, float* __restrict__ xgT, float* __restrict__ reg_out)
{
  __shared__ float scsh[2];
  __shared__ float hpl[400];
  __shared__ float y1[100 * 16];
  __shared__ float y2l[192 * 16];
  const int tid = threadIdx.x;
  if (tid == 0) {
    reg_out[0] = 0.f;                      // zero reg scalar (gcreg runs after)
    float m  = st3[0] * (1.f / kS);
    float vr = st3[1] * (1.f / kS) - m * m;
    float sc = fg3[0] * rsqrtf(vr + EPSV);
    scsh[0] = sc; scsh[1] = fbe3[0] - m * sc;
  }
  __syncthreads();
  {
    const float sc = scsh[0], sh = scsh[1];
    float ps[25];
    #pragma unroll
    for (int vv = 0; vv < 25; vv++) ps[vv] = 0.f;
    #pragma unroll
    for (int it = 0; it < 50; it++) {
      const int base = tid * 400 + it * 8;
      const bf16x8 v8 = *(const bf16x8*)&y3[base];
      #pragma unroll
      for (int e = 0; e < 8; e++) {
        const int vv = (it * 8 + e) % 25;          // compile-time per (it,e)
        ps[vv] += fmaxf(fmaf(bf2f(v8[e]), sc, sh), 0.f);
      }
    }
    #pragma unroll
    for (int vv = 0; vv < 25; vv++) {
      float v = ps[vv];
      v += __shfl_xor(v, 1); v += __shfl_xor(v, 2);
      v += __shfl_xor(v, 4); v += __shfl_xor(v, 8);
      if ((tid & 15) == 0) hpl[(tid >> 4) * 25 + vv] = v * (1.f / kT);  // b = tid/16
    }
  }
  __syncthreads();
  for (int j = tid; j < 1600; j += 256) {
    int o = j >> 4, b = j & 15;
    float acc = cb0[o];
    for (int v = 0; v < 25; v++) acc = fmaf(hpl[b * 25 + v], cw0[o * 25 + v], acc);
    y1[o * 16 + b] = acc;
  }
  __syncthreads();
  if (tid < 100) {
    float s1 = 0.f, s2 = 0.f;
    for (int b = 0; b < 16; b++) { float val = y1[tid * 16 + b]; s1 += val; s2 += val * val; }
    float m = s1 * (1.f / 16), vr = s2 * (1.f / 16) - m * m;
    float scale = cg0[tid] * rsqrtf(vr + EPSV);
    float shift = cbe0[tid] - m * scale;
    for (int b = 0; b < 16; b++)
      y1[tid * 16 + b] = fmaxf(fmaf(y1[tid * 16 + b], scale, shift), 0.f);
  }
  __syncthreads();
  for (int j = tid; j < 3072; j += 256) {
    int o = j >> 4, b = j & 15;
    float acc = cb1[o];
    for (int c = 0; c < 100; c++) acc = fmaf(y1[c * 16 + b], cw1[o * 100 + c], acc);
    y2l[o * 16 + b] = acc;
  }
  __syncthreads();
  if (tid < 192) {
    float s1 = 0.f, s2 = 0.f;
    for (int b = 0; b < 16; b++) { float val = y2l[tid * 16 + b]; s1 += val; s2 += val * val; }
    float m = s1 * (1.f / 16), vr = s2 * (1.f / 16) - m * m;
    float scale = cg1[tid] * rsqrtf(vr + EPSV);
    float shift = cbe1[tid] - m * scale;
    for (int b = 0; b < 16; b++) {
      float r = fmaxf(fmaf(y2l[tid * 16 + b], scale, shift), 0.f);
      xg[b * 192 + tid]  = r;
      xgT[tid * 16 + b]  = r;
    }
  }
}

// ---- K6: conv (blocks 0..1199) + gc/reg (blocks 1200..1824) merged ----
// Both depend only on head2's XG/XGT; merging deletes one graph node and
// co-schedules gcreg's light blocks under conv's long blocks.
__global__ __launch_bounds__(256) void conv_gcreg(
    const short* __restrict__ XSG, const short* __restrict__ WBBF,
    const float* __restrict__ XG, const float* __restrict__ XGT,
    const float* __restrict__ Ww, const float* __restrict__ Wb,
    const float* __restrict__ x, const float* __restrict__ bb,
    const float* __restrict__ bw,
    float* __restrict__ out_loss, float* __restrict__ gc_out,
    float* __restrict__ reg_out)
{
  __shared__ __align__(16) short xs[264 * 40];    // 21120 B
  __shared__ __align__(16) short As[48 * 104];    // 9984 B
  __shared__ __align__(16) float gw[25 * 204];    // 20400 B, stride 204
  __shared__ float bbl[192], bwl[32];

  const int tid = threadIdx.x;

  if (blockIdx.x >= 1200) {                        // ---- gcreg branch (625 blocks) ----
    float* sW = (float*)xs;                        // 576 floats (branch-exclusive LDS reuse)
    float* sG = (float*)gw;                        // 3264 floats
    const int u = blockIdx.x - 1200;
    const int v1 = u / 25, v2 = u - v1 * 25;
    for (int j = tid; j < 3072; j += 256) {
      int o = j >> 4, bq = j & 15;
      sG[o * 17 + bq] = XGT[j];
    }
    for (int p = tid; p < 192; p += 256) {
      int i = p / 48, m = p - i * 48;
      const float* src = Wb + ((i * 25 + v1) * 48 + m) * 75 + v2 * 3;
      sW[p * 3 + 0] = src[0]; sW[p * 3 + 1] = src[1]; sW[p * 3 + 2] = src[2];
    }
    __syncthreads();
    if (tid < 64) {
      const int b = tid & 15, c = tid >> 4;
      float s0 = 0.f, s1 = 0.f, s2 = 0.f, mx = -3.0e38f;
      #pragma unroll 4
      for (int o = c * 48; o < c * 48 + 48; o++) {
        float g = sG[o * 17 + b];
        float a0 = sW[o * 3] * g, a1 = sW[o * 3 + 1] * g, a2 = sW[o * 3 + 2] * g;
        s0 = fmaf(a0, a0, s0);
        s1 = fmaf(a1, a1, s1);
        s2 = fmaf(a2, a2, s2);
        mx = fmaxf(mx, fmaxf(fmaxf(a0, a1), a2));
      }
      s0 += __shfl_xor(s0, 16); s0 += __shfl_xor(s0, 32);
      s1 += __shfl_xor(s1, 16); s1 += __shfl_xor(s1, 32);
      s2 += __shfl_xor(s2, 16); s2 += __shfl_xor(s2, 32);
      mx = fmaxf(mx, __shfl_xor(mx, 16)); mx = fmaxf(mx, __shfl_xor(mx, 32));
      float contrib = 0.f;
      if (c == 0) {
        gc_out[(b * 25 + v1) * 25 + v2] = mx;
        contrib = sqrtf(s0 + s1 + s2) + sqrtf(s0) + sqrtf(s1) + sqrtf(s2);
      }
      #pragma unroll
      for (int d = 1; d < 16; d <<= 1) contrib += __shfl_xor(contrib, d);
      if (tid == 0) atomicAdd(reg_out, 0.01f * contrib);
    }
    return;
  }

  // ---- conv branch (blocks 0..1199) ----
  const int v = blockIdx.x % 25, n = blockIdx.x / 25;
  const int bidx = n / 3;

  {
    const uint4* src = (const uint4*)(XSG + n * 10560);
    uint4* dst = (uint4*)xs;
    for (int j = tid; j < 1320; j += 256) dst[j] = src[j];
  }
  for (int j = tid; j < 4800; j += 256) {          // gw = XG[bidx] * Ww
    int vv = j / 192, o = j - vv * 192;
    gw[vv * 204 + o] = XG[bidx * 192 + o] * Ww[j];
  }
  for (int j = tid; j < 192; j += 256) {
    int i = j / 48, m = j - i * 48;
    bbl[j] = bb[(i * 25 + v) * 48 + m];
  }
  if (tid < 25) bwl[tid] = bw[tid];

  const int lane = tid & 63, w = tid >> 6;
  const int c = lane & 15, q = lane >> 4;

  float accout[4] = {0.f, 0.f, 0.f, 0.f};
  int tarr[4], vparr[4];
  #pragma unroll
  for (int z = 0; z < 4; z++) {
    int t = (w * 4 + z) * 16 + c;
    tarr[z] = t;
    vparr[z] = (v * 256 + t) % 25;
  }

  for (int i = 0; i < 4; i++) {
    __syncthreads();                               // covers initial staging too
    {
      const uint4* src = (const uint4*)(WBBF + (i * 25 + v) * 4992);
      uint4* dst = (uint4*)As;
      for (int j = tid; j < 624; j += 256) dst[j] = src[j];
    }
    __syncthreads();

    const int d = i + 1;
    bf16x8 af[3][3];
    #pragma unroll
    for (int mt = 0; mt < 3; mt++)
      #pragma unroll
      for (int s = 0; s < 3; s++)
        af[mt][s] = *(const bf16x8*)&As[(mt * 16 + c) * 104 + s * 32 + q * 8];

    #pragma unroll
    for (int z = 0; z < 4; z++) {
      const int t = tarr[z];
      bf16x8 bfv[3];
      #pragma unroll
      for (int s = 0; s < 3; s++) {
        int row = 8 + t + (s - 2) * d;             // taps at t-2d, t-d, t
        bfv[s] = *(const bf16x8*)&xs[row * 40 + q * 8];
      }
      f32x4 acc[3] = {{0.f,0.f,0.f,0.f},{0.f,0.f,0.f,0.f},{0.f,0.f,0.f,0.f}};
      #pragma unroll
      for (int s = 0; s < 3; s++)
        #pragma unroll
        for (int mt = 0; mt < 3; mt++)
          acc[mt] = __builtin_amdgcn_mfma_f32_16x16x32_bf16(af[mt][s], bfv[s], acc[mt], 0, 0, 0);
      const int vp = vparr[z];
      float aout = 0.f;
      #pragma unroll
      for (int mt = 0; mt < 3; mt++) {
        const int ob = i * 48 + mt * 16 + q * 4;
        const float4 g4 = *(const float4*)&gw[vp * 204 + ob];
        float v0 = fmaxf(acc[mt][0] + bbl[ob + 0], 0.f);
        float v1 = fmaxf(acc[mt][1] + bbl[ob + 1], 0.f);
        float v2 = fmaxf(acc[mt][2] + bbl[ob + 2], 0.f);
        float v3 = fmaxf(acc[mt][3] + bbl[ob + 3], 0.f);
        aout = fmaf(v0, g4.x, aout);
        aout = fmaf(v1, g4.y, aout);
        aout = fmaf(v2, g4.z, aout);
        aout = fmaf(v3, g4.w, aout);
      }
      accout[z] += aout;
    }
  }

  #pragma unroll
  for (int z = 0; z < 4; z++) {
    float a = accout[z];
    a += __shfl_xor(a, 16);
    a += __shfl_xor(a, 32);
    if (q == 0) {
      int flat = v * 256 + tarr[z];
      int tp = flat / 25, vp = flat - tp * 25;
      if (tp < 255) {
        float pf = a + bwl[vp];
        float xn = x[n * 6400 + (tp + 1) * 25 + vp];
        float dd = pf - xn;
        out_loss[(n * 25 + vp) * 255 + tp] = dd * dd;
      }
    }
  }
}

extern "C" void kernel_launch(void* const* d_in, const int* in_sizes, int n_in,
                              void* d_out, int out_size, void* d_ws, size_t ws_size,
                              hipStream_t stream)
{
  const float* x    = (const float*)d_in[0];
  const float* Wb   = (const float*)d_in[1];
  const float* bb   = (const float*)d_in[2];
  const float* fw0  = (const float*)d_in[3];
  const float* fb0  = (const float*)d_in[4];
  const float* fg0  = (const float*)d_in[5];
  const float* fbe0 = (const float*)d_in[6];
  const float* fw1  = (const float*)d_in[7];
  const float* fb1  = (const float*)d_in[8];
  const float* fg1  = (const float*)d_in[9];
  const float* fbe1 = (const float*)d_in[10];
  const float* fw2  = (const float*)d_in[11];
  const float* fb2  = (const float*)d_in[12];
  const float* fg2  = (const float*)d_in[13];
  const float* fbe2 = (const float*)d_in[14];
  const float* fw3  = (const float*)d_in[15];
  const float* fb3  = (const float*)d_in[16];
  const float* fg3  = (const float*)d_in[17];
  const float* fbe3 = (const float*)d_in[18];
  const float* cw0  = (const float*)d_in[19];
  const float* cb0  = (const float*)d_in[20];
  const float* cg0  = (const float*)d_in[21];
  const float* cbe0 = (const float*)d_in[22];
  const float* cw1  = (const float*)d_in[23];
  const float* cb1  = (const float*)d_in[24];
  const float* cg1  = (const float*)d_in[25];
  const float* cbe1 = (const float*)d_in[26];
  const float* Ww   = (const float*)d_in[27];
  const float* bw   = (const float*)d_in[28];

  float* ws  = (float*)d_ws;
  float* out = (float*)d_out;

  float* XMOM  = ws;                      // 9
  float* H0MOM = ws + 16;                 // 65
  float* ST2   = ws + 96;                 // 20
  float* ST3   = ws + 128;                // 2 (sum, sumsq)
  float* XG    = ws + 608;                // 3072
  float* XGT   = ws + 3680;               // 3072
  short* ACC   = (short*)(ws + 8192);     // 10*kS shorts
  short* Y3    = (short*)(ws + 520192);   // 102400 shorts
  short* WBBF  = (short*)(ws + 571392);   // 499200 shorts
  short* XSG   = (short*)(ws + 820992);   // 506880 shorts

  zero_stats<<<3, 256, 0, stream>>>(ws);

  prep_xmom<<<800, 128, 0, stream>>>(x, Wb, XSG, WBBF, XMOM);
  h0mom_kernel<<<800, 128, 0, stream>>>(x, fw0, fb0, fg0, fbe0, XMOM, H0MOM);
  st2acc<<<800, 128, 0, stream>>>(x, fw0, fb0, fg0, fbe0, fw1, fb1, fg1, fbe1,
      fw2, fb2, XMOM, H0MOM, ACC, ST2);
  h2y3<<<800, 128, 0, stream>>>(ACC, fg2, fbe2, fw3, fb3, ST2, Y3, ST3);
  head2_kernel<<<1, 256, 0, stream>>>(Y3, ST3, fg3, fbe3,
      cw0, cb0, cg0, cbe0, cw1, cb1, cg1, cbe1, XG, XGT, out + 316000);
  conv_gcreg<<<1825, 256, 0, stream>>>(XSG, WBBF, XG, XGT, Ww, Wb, x, bb, bw,
      out, out + 306000, out + 316000);
}